// Round 1
// baseline (624.996 us; speedup 1.0000x reference)
//
#include <hip/hip_runtime.h>

// Laplacian pyramid build: im (16,3,1024,1024) fp32, levels=5.
// Output = concat(lpyr[0..4]) flat. P = 48 planes (B*C).
//
// Pass 1: gpyr[l+1] = reduce(gpyr[l]) written straight into out slice l+1
//         (slice 4 == lpyr[4], done).
// Pass 2: for l = 0..3 (increasing): slice_l = gpyr[l] - expand(slice_{l+1}),
//         in place for l>=1 (gpyr[0] = input im).

__device__ __constant__ float c_h5[5] = {0.0625f, 0.25f, 0.375f, 0.25f, 0.0625f};

// ---------------- reduce: 5x5 binomial, stride 2, edge clamp ----------------
__launch_bounds__(256)
__global__ void reduce_kernel(const float* __restrict__ in, float* __restrict__ out,
                              int Hin, int Win, int Hout, int Wout) {
    int j = blockIdx.x * blockDim.x + threadIdx.x;
    int i = blockIdx.y * blockDim.y + threadIdx.y;
    int p = blockIdx.z;
    if (i >= Hout || j >= Wout) return;

    const float* src = in + (size_t)p * Hin * Win;

    // column indices 2j-2 .. 2j+2 clamped
    int c[5];
#pragma unroll
    for (int b = 0; b < 5; ++b) {
        int cc = 2 * j - 2 + b;
        c[b] = cc < 0 ? 0 : (cc >= Win ? Win - 1 : cc);
    }

    float acc = 0.f;
#pragma unroll
    for (int a = 0; a < 5; ++a) {
        int r = 2 * i - 2 + a;
        r = r < 0 ? 0 : (r >= Hin ? Hin - 1 : r);
        const float* row = src + (size_t)r * Win;
        float s;
        s = 0.0625f * row[c[0]];
        s = fmaf(0.25f,   row[c[1]], s);
        s = fmaf(0.375f,  row[c[2]], s);
        s = fmaf(0.25f,   row[c[3]], s);
        s = fmaf(0.0625f, row[c[4]], s);
        acc = fmaf(c_h5[a], s, acc);
    }
    out[(size_t)p * Hout * Wout + (size_t)i * Wout + j] = acc;
}

// ------------- lpyr[l] = fine - expand(coarse); thread per coarse pixel -------------
// Even output phase (row/col 2i): coarse taps (i-1,i,i+1) w (0.125,0.75,0.125)
// Odd  output phase (2i+1):       coarse taps (i,i+1)     w (0.5,0.5)
__launch_bounds__(256)
__global__ void lap_kernel(const float* __restrict__ fine, const float* __restrict__ coarse,
                           float* __restrict__ out, int Hc, int Wc) {
    int j = blockIdx.x * blockDim.x + threadIdx.x;
    int i = blockIdx.y * blockDim.y + threadIdx.y;
    int p = blockIdx.z;
    if (i >= Hc || j >= Wc) return;

    const float* g = coarse + (size_t)p * Hc * Wc;
    int im1 = i > 0 ? i - 1 : 0;
    int ip1 = i < Hc - 1 ? i + 1 : Hc - 1;
    int jm1 = j > 0 ? j - 1 : 0;
    int jp1 = j < Wc - 1 ? j + 1 : Wc - 1;

    const float* rm = g + (size_t)im1 * Wc;
    const float* r0 = g + (size_t)i   * Wc;
    const float* rp = g + (size_t)ip1 * Wc;

    float g00 = rm[jm1], g01 = rm[j], g02 = rm[jp1];
    float g10 = r0[jm1], g11 = r0[j], g12 = r0[jp1];
    float g20 = rp[jm1], g21 = rp[j], g22 = rp[jp1];

    // row-direction combos per column
    float e0 = fmaf(0.125f, g00, fmaf(0.75f, g10, 0.125f * g20)); // even row, col j-1
    float e1 = fmaf(0.125f, g01, fmaf(0.75f, g11, 0.125f * g21)); // even row, col j
    float e2 = fmaf(0.125f, g02, fmaf(0.75f, g12, 0.125f * g22)); // even row, col j+1
    float o0 = 0.5f * (g10 + g20);                                 // odd row, col j-1
    float o1 = 0.5f * (g11 + g21);
    float o2 = 0.5f * (g12 + g22);

    float e00 = fmaf(0.125f, e0, fmaf(0.75f, e1, 0.125f * e2)); // out(2i  ,2j  )
    float e01 = 0.5f * (e1 + e2);                                // out(2i  ,2j+1)
    float e10 = fmaf(0.125f, o0, fmaf(0.75f, o1, 0.125f * o2)); // out(2i+1,2j  )
    float e11 = 0.5f * (o1 + o2);                                // out(2i+1,2j+1)

    int Wf = 2 * Wc;
    size_t fbase = (size_t)p * (size_t)(2 * Hc) * Wf;
    const float2* f0 = (const float2*)(fine + fbase + (size_t)(2 * i) * Wf);
    const float2* f1 = (const float2*)(fine + fbase + (size_t)(2 * i + 1) * Wf);
    float2 a = f0[j], b = f1[j];

    float2* w0 = (float2*)(out + fbase + (size_t)(2 * i) * Wf);
    float2* w1 = (float2*)(out + fbase + (size_t)(2 * i + 1) * Wf);
    w0[j] = make_float2(a.x - e00, a.y - e01);
    w1[j] = make_float2(b.x - e10, b.y - e11);
}

extern "C" void kernel_launch(void* const* d_in, const int* in_sizes, int n_in,
                              void* d_out, int out_size, void* d_ws, size_t ws_size,
                              hipStream_t stream) {
    (void)in_sizes; (void)n_in; (void)d_ws; (void)ws_size; (void)out_size;
    const float* im = (const float*)d_in[0];
    float* out = (float*)d_out;

    const int P = 48;           // 16 * 3 planes
    const int H0 = 1024, W0 = 1024;

    // slice offsets in out
    size_t off[5];
    size_t acc = 0;
    for (int l = 0; l < 5; ++l) {
        off[l] = acc;
        int h = H0 >> l, w = W0 >> l;
        acc += (size_t)P * h * w;
    }

    dim3 blk(64, 4, 1);

    // Pass 1: reduce chain -> slices 1..4 hold gpyr[1..4]
    for (int l = 0; l < 4; ++l) {
        int Hin = H0 >> l, Win = W0 >> l;
        int Hout = Hin >> 1, Wout = Win >> 1;
        const float* src = (l == 0) ? im : (out + off[l]);
        float* dst = out + off[l + 1];
        dim3 grid((Wout + blk.x - 1) / blk.x, (Hout + blk.y - 1) / blk.y, P);
        reduce_kernel<<<grid, blk, 0, stream>>>(src, dst, Hin, Win, Hout, Wout);
    }

    // Pass 2: laplacian levels 0..3 (increasing l so gpyr[l+1] is intact)
    for (int l = 0; l < 4; ++l) {
        int Hc = H0 >> (l + 1), Wc = W0 >> (l + 1);
        const float* fine = (l == 0) ? im : (out + off[l]);
        const float* coarse = out + off[l + 1];
        float* dst = out + off[l];
        dim3 grid((Wc + blk.x - 1) / blk.x, (Hc + blk.y - 1) / blk.y, P);
        lap_kernel<<<grid, blk, 0, stream>>>(fine, coarse, dst, Hc, Wc);
    }
}

// Round 2
// 580.200 us; speedup vs baseline: 1.0772x; 1.0772x over previous
//
#include <hip/hip_runtime.h>

// Laplacian pyramid build: im (16,3,1024,1024) fp32, levels=5. P = 48 planes.
// Pass 1: gpyr[l+1] = reduce(gpyr[l]) written into out slice l+1 (slice 4 == lpyr[4]).
// Pass 2: slice_l = gpyr[l] - expand(slice_{l+1}), in place (increasing l).

// ---------------- reduce: 5x5 binomial, stride 2, edge clamp, LDS-tiled ----------------
// Block (64,4) -> 64x4 output tile; input tile 132 x 12 staged in LDS with
// coalesced consecutive-dword loads. Compute reads are stride-2 in LDS
// (2-way bank alias = conflict-free on gfx950).
#define RTX 64
#define RTY 4
#define LDSW 132

__launch_bounds__(256)
__global__ void reduce_kernel(const float* __restrict__ in, float* __restrict__ out,
                              int Hin, int Win, int Hout, int Wout) {
    __shared__ float tile[12 * LDSW];
    const int tx = threadIdx.x, ty = threadIdx.y;
    const int p = blockIdx.z;
    const float* src = in + (size_t)p * Hin * Win;

    const int row0 = 2 * (blockIdx.y * RTY) - 2;
    const int col0 = 2 * (blockIdx.x * RTX) - 2;

    // ---- stage input tile (clamped) ----
#pragma unroll
    for (int r = ty; r < 12; r += RTY) {
        int gr = row0 + r;
        gr = gr < 0 ? 0 : (gr >= Hin ? Hin - 1 : gr);
        const float* srow = src + (size_t)gr * Win;
#pragma unroll
        for (int c = tx; c < LDSW; c += RTX) {
            int gc = col0 + c;
            gc = gc < 0 ? 0 : (gc >= Win ? Win - 1 : gc);
            tile[r * LDSW + c] = srow[gc];
        }
    }
    __syncthreads();

    const int j = blockIdx.x * RTX + tx;
    const int i = blockIdx.y * RTY + ty;
    if (i >= Hout || j >= Wout) return;

    const float w0 = 0.0625f, w1 = 0.25f, w2 = 0.375f;
    const float* trow = tile + (2 * ty) * LDSW + 2 * tx;
    float acc = 0.f;
    const float wr[5] = {w0, w1, w2, w1, w0};
#pragma unroll
    for (int a = 0; a < 5; ++a) {
        const float* rr = trow + a * LDSW;
        float s = w0 * rr[0];
        s = fmaf(w1, rr[1], s);
        s = fmaf(w2, rr[2], s);
        s = fmaf(w1, rr[3], s);
        s = fmaf(w0, rr[4], s);
        acc = fmaf(wr[a], s, acc);
    }
    out[(size_t)p * Hout * Wout + (size_t)i * Wout + j] = acc;
}

// ------------- lpyr[l] = fine - expand(coarse); thread per 2 coarse cols -------------
// Even output row (2i): coarse rows (i-1,i,i+1) w (0.125,0.75,0.125)
// Odd  output row (2i+1): coarse rows (i,i+1)   w (0.5,0.5); same in columns.
// Each thread covers coarse cols {2t,2t+1} -> fine cols 4t..4t+3, rows 2i,2i+1:
// fine load + out store are float4 (16 B/lane).
__launch_bounds__(256)
__global__ void lap_kernel(const float* __restrict__ fine, const float* __restrict__ coarse,
                           float* __restrict__ out, int Hc, int Wc) {
    const int t = blockIdx.x * blockDim.x + threadIdx.x;  // coarse col-pair index
    const int i = blockIdx.y * blockDim.y + threadIdx.y;  // coarse row
    const int p = blockIdx.z;
    const int Wc2 = Wc >> 1;
    if (i >= Hc || t >= Wc2) return;

    const float* g = coarse + (size_t)p * Hc * Wc;
    const int im1 = i > 0 ? i - 1 : 0;
    const int ip1 = i < Hc - 1 ? i + 1 : Hc - 1;
    const float* rm = g + (size_t)im1 * Wc;
    const float* r0 = g + (size_t)i   * Wc;
    const float* rp = g + (size_t)ip1 * Wc;

    const int jl = 2 * t - 1 > 0 ? 2 * t - 1 : 0;             // clamp(2t-1)
    const int jr = 2 * t + 2 < Wc - 1 ? 2 * t + 2 : Wc - 1;   // clamp(2t+2)

    // coarse cols 2t-1, 2t, 2t+1, 2t+2 for three rows
    float cm[4], c0[4], cp[4];
    {
        float2 m = *(const float2*)(rm + 2 * t);
        float2 z = *(const float2*)(r0 + 2 * t);
        float2 q = *(const float2*)(rp + 2 * t);
        cm[1] = m.x; cm[2] = m.y;
        c0[1] = z.x; c0[2] = z.y;
        cp[1] = q.x; cp[2] = q.y;
        cm[0] = rm[jl]; cm[3] = rm[jr];
        c0[0] = r0[jl]; c0[3] = r0[jr];
        cp[0] = rp[jl]; cp[3] = rp[jr];
    }

    float e[4], o[4];
#pragma unroll
    for (int c = 0; c < 4; ++c) {
        e[c] = fmaf(0.125f, cm[c], fmaf(0.75f, c0[c], 0.125f * cp[c]));
        o[c] = 0.5f * (c0[c] + cp[c]);
    }

    // horizontal combine: out cols 4t..4t+3
    float ev0 = fmaf(0.125f, e[0], fmaf(0.75f, e[1], 0.125f * e[2]));
    float ev1 = 0.5f * (e[1] + e[2]);
    float ev2 = fmaf(0.125f, e[1], fmaf(0.75f, e[2], 0.125f * e[3]));
    float ev3 = 0.5f * (e[2] + e[3]);
    float od0 = fmaf(0.125f, o[0], fmaf(0.75f, o[1], 0.125f * o[2]));
    float od1 = 0.5f * (o[1] + o[2]);
    float od2 = fmaf(0.125f, o[1], fmaf(0.75f, o[2], 0.125f * o[3]));
    float od3 = 0.5f * (o[2] + o[3]);

    const int Wf = 2 * Wc;
    const size_t fbase = (size_t)p * (size_t)(2 * Hc) * Wf;
    const float4* f0 = (const float4*)(fine + fbase + (size_t)(2 * i) * Wf);
    const float4* f1 = (const float4*)(fine + fbase + (size_t)(2 * i + 1) * Wf);
    float4 a = f0[t], b = f1[t];

    float4* w0p = (float4*)(out + fbase + (size_t)(2 * i) * Wf);
    float4* w1p = (float4*)(out + fbase + (size_t)(2 * i + 1) * Wf);
    w0p[t] = make_float4(a.x - ev0, a.y - ev1, a.z - ev2, a.w - ev3);
    w1p[t] = make_float4(b.x - od0, b.y - od1, b.z - od2, b.w - od3);
}

extern "C" void kernel_launch(void* const* d_in, const int* in_sizes, int n_in,
                              void* d_out, int out_size, void* d_ws, size_t ws_size,
                              hipStream_t stream) {
    (void)in_sizes; (void)n_in; (void)d_ws; (void)ws_size; (void)out_size;
    const float* im = (const float*)d_in[0];
    float* out = (float*)d_out;

    const int P = 48;           // 16 * 3 planes
    const int H0 = 1024, W0 = 1024;

    size_t off[5];
    size_t acc = 0;
    for (int l = 0; l < 5; ++l) {
        off[l] = acc;
        int h = H0 >> l, w = W0 >> l;
        acc += (size_t)P * h * w;
    }

    // Pass 1: reduce chain -> slices 1..4 hold gpyr[1..4]
    for (int l = 0; l < 4; ++l) {
        int Hin = H0 >> l, Win = W0 >> l;
        int Hout = Hin >> 1, Wout = Win >> 1;
        const float* src = (l == 0) ? im : (out + off[l]);
        float* dst = out + off[l + 1];
        dim3 blk(RTX, RTY, 1);
        dim3 grid((Wout + RTX - 1) / RTX, (Hout + RTY - 1) / RTY, P);
        reduce_kernel<<<grid, blk, 0, stream>>>(src, dst, Hin, Win, Hout, Wout);
    }

    // Pass 2: laplacian levels 0..3 (increasing l so gpyr[l+1] is intact)
    for (int l = 0; l < 4; ++l) {
        int Hc = H0 >> (l + 1), Wc = W0 >> (l + 1);
        const float* fine = (l == 0) ? im : (out + off[l]);
        const float* coarse = out + off[l + 1];
        float* dst = out + off[l];
        dim3 blk(64, 4, 1);
        dim3 grid((Wc / 2 + 63) / 64, (Hc + 3) / 4, P);
        lap_kernel<<<grid, blk, 0, stream>>>(fine, coarse, dst, Hc, Wc);
    }
}